// Round 15
// baseline (2383.476 us; speedup 1.0000x reference)
//
#include <hip/hip_runtime.h>
#include <stdint.h>

#define NB 8
#define NT 1024
#define ND 768
#define NV 768
#define NL 13
#define MTOK (NB*NT)          // 8192
#define MROWS (MTOK*NL)       // 106496

typedef __attribute__((ext_vector_type(8))) short short8;
typedef __attribute__((ext_vector_type(4))) float f32x4;

__device__ __forceinline__ unsigned short f2bf(float f) {
    union { float f; unsigned u; } v; v.f = f;
    unsigned r = v.u + 0x7FFFu + ((v.u >> 16) & 1u);
    return (unsigned short)(r >> 16);
}
__device__ __forceinline__ float bf2f(unsigned short u) {
    union { unsigned u; float f; } v; v.u = ((unsigned)u) << 16;
    return v.f;
}
__device__ __forceinline__ unsigned cvtpk(float lo, float hi) {
    unsigned r;
    asm("v_cvt_pk_bf16_f32 %0, %1, %2" : "=v"(r) : "v"(lo), "v"(hi));
    return r;
}
__device__ __forceinline__ void gload16(const void* g, void* l) {
    __builtin_amdgcn_global_load_lds(
        (const __attribute__((address_space(1))) unsigned int*)g,
        (__attribute__((address_space(3))) unsigned int*)l, 16, 0, 0);
}

#define PHB { __builtin_amdgcn_s_barrier(); __builtin_amdgcn_sched_barrier(0); }

// ---------------------------------------------------------------------------
// fp32 -> bf16 bulk convert (weights only)
// ---------------------------------------------------------------------------
__global__ __launch_bounds__(256) void conv_f32_bf16(
    const float* __restrict__ s, unsigned short* __restrict__ d, long n)
{
    long i = ((long)blockIdx.x * 256 + threadIdx.x) * 8;
    long st = (long)gridDim.x * 2048;
    for (; i < n; i += st) {
        float4 a = *(const float4*)(s + i);
        float4 b = *(const float4*)(s + i + 4);
        ushort4 u0, u1;
        u0.x = f2bf(a.x); u0.y = f2bf(a.y); u0.z = f2bf(a.z); u0.w = f2bf(a.w);
        u1.x = f2bf(b.x); u1.y = f2bf(b.y); u1.z = f2bf(b.z); u1.w = f2bf(b.w);
        *(ushort4*)(d + i)     = u0;
        *(ushort4*)(d + i + 4) = u1;
    }
}

// ---------------------------------------------------------------------------
// GEMM1: C(bf16) = A(fp32) * B(bf16)^T + bias.  K=768, BK=32, 24 K-tiles.
// 256x256 tile, 8 waves (2M x 4N), per-wave 128x64.
// R12/R14 structure (chunk-major LDS, reg staging, 1-barrier tiles) with
// TWO LDS buffers (64 KB) -> 2 blocks/CU: inter-block TLP (m114) covers the
// per-tile drain+barrier that 1-block/CU couldn't hide.
// Reg pipeline: tile j loaded into regs[j&1] at tile j-2, written to
// buf[j&1] at tile j-1; buf ring of 2 is hazard-free (write lands in the
// buffer whose last read ended at the previous barrier).
// ---------------------------------------------------------------------------
__global__ __launch_bounds__(512, 4) void gemm_f32a(
    const float* __restrict__ A, const unsigned short* __restrict__ B,
    const float* __restrict__ biasBase, unsigned short* __restrict__ C,
    long aLS, long bLS, int biasLS, long cLayerOff, long cRowStride)
{
    __shared__ __align__(16) unsigned short lsA[2][4 * 256 * 8];  // 16KB/buf
    __shared__ __align__(16) unsigned short lsB[2][4 * 256 * 8];

    const int bid = blockIdx.x;
    const int xcd = bid & 7, slot = bid >> 3;        // 156 slots per XCD
    const int grp = xcd * 52 + slot / 3;             // 0..415
    const int nx  = slot % 3;
    const int l   = grp >> 5;                        // layer 0..12
    const long m0 = (long)(grp & 31) * 256;
    const long n0 = (long)nx * 256;

    const int t = threadIdx.x, lane = t & 63, wave = t >> 6;

    const float* Ab = A + (size_t)l * aLS;
    const unsigned short* Bb = B + (size_t)l * bLS;
    const float* bias = biasBase + (size_t)l * biasLS;

    // staging: thread covers row t>>1 (0..255), k-half t&1 (16 elems)
    const int sRow  = t >> 1;
    const int sHalf = t & 1;
    const float* aSrc = Ab + (m0 + sRow) * (size_t)768 + sHalf * 16;
    const unsigned short* bSrc = Bb + (n0 + sRow) * (size_t)768 + sHalf * 16;

    const int wm = (wave >> 2) * 128;    // 2 M-wave groups
    const int wn = (wave & 3) * 64;      // 4 N-wave groups
    const int lr = lane & 15;
    const int g4 = lane >> 4;

    f32x4 acc[8][4];
#pragma unroll
    for (int i = 0; i < 8; i++)
#pragma unroll
        for (int j = 0; j < 4; j++) acc[i][j] = (f32x4){0.f, 0.f, 0.f, 0.f};

    f32x4 ra0[4], ra1[4];
    short8 rb0[2], rb1[2];

#define LOADA(R, K0) { _Pragma("unroll") \
    for (int i_ = 0; i_ < 4; i_++) (R)[i_] = *(const f32x4*)(aSrc + (K0) + i_ * 4); }
#define LOADB(R, K0) { _Pragma("unroll") \
    for (int j_ = 0; j_ < 2; j_++) (R)[j_] = *(const short8*)(bSrc + (K0) + j_ * 8); }
#define WRITEA(R, BUF) { unsigned short* la_ = lsA[BUF]; \
    uint4 w0_, w1_; \
    w0_.x = cvtpk((R)[0][0], (R)[0][1]); w0_.y = cvtpk((R)[0][2], (R)[0][3]); \
    w0_.z = cvtpk((R)[1][0], (R)[1][1]); w0_.w = cvtpk((R)[1][2], (R)[1][3]); \
    w1_.x = cvtpk((R)[2][0], (R)[2][1]); w1_.y = cvtpk((R)[2][2], (R)[2][3]); \
    w1_.z = cvtpk((R)[3][0], (R)[3][1]); w1_.w = cvtpk((R)[3][2], (R)[3][3]); \
    *(uint4*)&la_[(2 * sHalf + 0) * 2048 + sRow * 8] = w0_; \
    *(uint4*)&la_[(2 * sHalf + 1) * 2048 + sRow * 8] = w1_; }
#define WRITEB(R, BUF) { unsigned short* lb_ = lsB[BUF]; \
    *(short8*)&lb_[(2 * sHalf + 0) * 2048 + sRow * 8] = (R)[0]; \
    *(short8*)&lb_[(2 * sHalf + 1) * 2048 + sRow * 8] = (R)[1]; }

    // Merged single-window tile: loads, frag reads, 32 MFMA, writes, 1 barrier.
#define TILE(KS, RLA, RLB, RWA, RWB, DOL, DOW) { \
    const unsigned short* pa_ = lsA[(KS) & 1]; \
    const unsigned short* pb_ = lsB[(KS) & 1]; \
    if (DOL) { LOADA(RLA, ((KS) + 2) * 32); LOADB(RLB, ((KS) + 2) * 32); } \
    short8 bv_[4], af_[8]; \
    _Pragma("unroll") \
    for (int ni_ = 0; ni_ < 4; ni_++) \
        bv_[ni_] = *(const short8*)&pb_[g4 * 2048 + (wn + ni_ * 16 + lr) * 8]; \
    _Pragma("unroll") \
    for (int mi_ = 0; mi_ < 8; mi_++) \
        af_[mi_] = *(const short8*)&pa_[g4 * 2048 + (wm + mi_ * 16 + lr) * 8]; \
    __builtin_amdgcn_s_setprio(1); \
    _Pragma("unroll") \
    for (int mi_ = 0; mi_ < 8; mi_++) \
        _Pragma("unroll") \
        for (int ni_ = 0; ni_ < 4; ni_++) \
            acc[mi_][ni_] = __builtin_amdgcn_mfma_f32_16x16x32_bf16( \
                af_[mi_], bv_[ni_], acc[mi_][ni_], 0, 0, 0); \
    __builtin_amdgcn_s_setprio(0); \
    if (DOW) { WRITEA(RWA, ((KS) + 1) & 1); WRITEB(RWB, ((KS) + 1) & 1); } \
    asm volatile("s_waitcnt lgkmcnt(0)" ::: "memory"); PHB; }

    // Prologue: tile0 -> regs -> LDS buf0; tile1 -> regs (pending, written
    // at tile0's body).  Compiler inserts the vmcnt waits for reg reads.
    LOADA(ra0, 0);  LOADB(rb0, 0);
    LOADA(ra1, 32); LOADB(rb1, 32);
    WRITEA(ra0, 0); WRITEB(rb0, 0);
    __syncthreads();

    // Steady: tile t computes buf[t&1]; loads tile t+2 into regs[t&1];
    // writes tile t+1 (regs[(t+1)&1]) into buf[(t+1)&1].
    for (int tp = 0; tp < 20; tp += 2) {
        TILE(tp,     ra0, rb0, ra1, rb1, 1, 1);
        TILE(tp + 1, ra1, rb1, ra0, rb0, 1, 1);
    }
    TILE(20, ra0, rb0, ra1, rb1, 1, 1);
    TILE(21, ra1, rb1, ra0, rb0, 1, 1);
    TILE(22, ra0, rb0, ra1, rb1, 0, 1);   // writes tile 23 (loaded at t=21)
    TILE(23, ra1, rb1, ra0, rb0, 0, 0);

#undef TILE
#undef WRITEB
#undef WRITEA
#undef LOADB
#undef LOADA

#pragma unroll
    for (int ni = 0; ni < 4; ni++) {
        long col = n0 + wn + ni * 16 + lr;
        float bvs = bias[col];
#pragma unroll
        for (int mi = 0; mi < 8; mi++) {
#pragma unroll
            for (int r = 0; r < 4; r++) {
                long grow = m0 + wm + mi * 16 + g4 * 4 + r;
                size_t coff = (size_t)grow * cRowStride + (size_t)l * cLayerOff + col;
                C[coff] = f2bf(acc[mi][ni][r] + bvs);
            }
        }
    }
}

// ---------------------------------------------------------------------------
// GEMM2: C(f32) = A(bf16) * B(bf16)^T + bias.  64x128 tile, BK=32, gload
// staging + XOR swizzle (R6/R10-verified), grid 768 = 8 x 16 x 6.
// ---------------------------------------------------------------------------
__global__ __launch_bounds__(256) void gemm_bf16_nt(
    const unsigned short* __restrict__ A, const unsigned short* __restrict__ B,
    const float* __restrict__ bias, float* __restrict__ C,
    int K, long cRowStride)
{
    __shared__ __align__(16) unsigned short lsA[2][64 * 32];
    __shared__ __align__(16) unsigned short lsB[2][128 * 32];

    const int bid = blockIdx.x;
    const int xcd = bid & 7, slot = bid >> 3;        // 96 slots per XCD
    const int grp = xcd * 16 + slot / 6;             // 0..127 m-blocks
    const int nx  = slot % 6;
    const long m0 = (long)grp * 64;
    const long n0 = (long)nx * 128;

    const int t = threadIdx.x, lane = t & 63, wave = t >> 6;

    const int srow = wave * 16 + (lane >> 2);        // 0..63
    const int schk = (lane & 3) ^ ((lane >> 3) & 3);
    const int dS   = wave * 1024 + lane * 16;

    const int wm = (wave >> 1) * 32;
    const int wn = (wave & 1) * 64;
    const int lr = lane & 15;
    const int g4 = lane >> 4;
    const int kg = g4 * 8;
    const int swz = ((lr >> 1) & 3) * 8;

    const unsigned short* aSp  = A + (m0 + srow) * (size_t)K + schk * 8;
    const unsigned short* bSp0 = B + (n0 + srow) * (size_t)K + schk * 8;
    const unsigned short* bSp1 = B + (n0 + 64 + srow) * (size_t)K + schk * 8;

    f32x4 acc[2][4];
#pragma unroll
    for (int i = 0; i < 2; i++)
#pragma unroll
        for (int j = 0; j < 4; j++) acc[i][j] = (f32x4){0.f, 0.f, 0.f, 0.f};

    auto STAGE = [&](int buf, int k0) {
        char* la = (char*)lsA[buf];
        char* lb = (char*)lsB[buf];
        gload16(aSp + k0, la + dS);
        gload16(bSp0 + k0, lb + dS);
        gload16(bSp1 + k0, lb + 4096 + dS);
    };
    auto COMP = [&](int buf) {
        short8 af[2], bv[4];
        const unsigned short* pa = lsA[buf];
        const unsigned short* pb = lsB[buf];
#pragma unroll
        for (int mi = 0; mi < 2; mi++)
            af[mi] = *(const short8*)&pa[(wm + mi * 16 + lr) * 32 + (kg ^ swz)];
#pragma unroll
        for (int ni = 0; ni < 4; ni++)
            bv[ni] = *(const short8*)&pb[(wn + ni * 16 + lr) * 32 + (kg ^ swz)];
#pragma unroll
        for (int mi = 0; mi < 2; mi++)
#pragma unroll
            for (int ni = 0; ni < 4; ni++)
                acc[mi][ni] = __builtin_amdgcn_mfma_f32_16x16x32_bf16(
                    af[mi], bv[ni], acc[mi][ni], 0, 0, 0);
    };

    STAGE(0, 0);
    __syncthreads();
    int cur = 0;
    const int nst = K >> 5;
    for (int ks = 1; ks < nst; ks++) {
        STAGE(cur ^ 1, ks * 32);
        COMP(cur);
        __syncthreads();
        cur ^= 1;
    }
    COMP(cur);

#pragma unroll
    for (int ni = 0; ni < 4; ni++) {
        long col = n0 + wn + ni * 16 + lr;
        float bvs = bias[col];
#pragma unroll
        for (int mi = 0; mi < 2; mi++) {
#pragma unroll
            for (int r = 0; r < 4; r++) {
                long grow = m0 + wm + mi * 16 + g4 * 4 + r;
                C[(size_t)grow * cRowStride + col] = acc[mi][ni][r] + bvs;
            }
        }
    }
}

// ---------------------------------------------------------------------------
// Fold kvln gamma into k_w; compute s_k = sum(kw*g), c_k = kw.b + k_bias.
// ---------------------------------------------------------------------------
__global__ __launch_bounds__(256) void wtrans(
    const float* __restrict__ kw, const float* __restrict__ kvg,
    const float* __restrict__ kvb, const float* __restrict__ kbias,
    float* __restrict__ kwp, float* __restrict__ skv, float* __restrict__ ckv)
{
    __shared__ float red[8];
    const int q = blockIdx.x, t = threadIdx.x;
    const int lane = t & 63, wave = t >> 6;
    float s = 0.f, c = 0.f;
    for (int v = t; v < 768; v += 256) {
        float w = kw[q * 768 + v];
        float wp = w * kvg[v];
        kwp[q * 768 + v] = wp;
        s += wp;
        c += w * kvb[v];
    }
#pragma unroll
    for (int off = 1; off < 64; off <<= 1) {
        s += __shfl_xor(s, off);
        c += __shfl_xor(c, off);
    }
    if (lane == 0) { red[wave] = s; red[4 + wave] = c; }
    __syncthreads();
    if (t == 0) {
        skv[q] = red[0] + red[1] + red[2] + red[3];
        ckv[q] = red[4] + red[5] + red[6] + red[7] + kbias[q];
    }
}

// ---------------------------------------------------------------------------
// LayerNorm rows of 768 (fp32 src) -> bf16.  Q side only.
// ---------------------------------------------------------------------------
__global__ __launch_bounds__(256) void ln_rows_f32(
    const float* __restrict__ src, unsigned short* __restrict__ dst,
    const float* __restrict__ gam, const float* __restrict__ bet)
{
    const int lane = threadIdx.x & 63;
    const int wave = threadIdx.x >> 6;
    const size_t row = (size_t)blockIdx.x * 4 + wave;

    float x[3][4];
    float s = 0.f, sq = 0.f;
#pragma unroll
    for (int i = 0; i < 3; i++) {
        int v = i * 256 + lane * 4;
        float4 f = *(const float4*)(src + row * 768 + v);
        x[i][0] = f.x; x[i][1] = f.y; x[i][2] = f.z; x[i][3] = f.w;
#pragma unroll
        for (int e = 0; e < 4; e++) { s += x[i][e]; sq += x[i][e] * x[i][e]; }
    }
#pragma unroll
    for (int off = 1; off < 64; off <<= 1) {
        s  += __shfl_xor(s, off);
        sq += __shfl_xor(sq, off);
    }
    float mean = s * (1.f / 768.f);
    float var  = sq * (1.f / 768.f) - mean * mean;
    float rs   = rsqrtf(var + 1e-5f);
#pragma unroll
    for (int i = 0; i < 3; i++) {
        int v = i * 256 + lane * 4;
        float4 gg = *(const float4*)(gam + v);
        float4 bb = *(const float4*)(bet + v);
        ushort4 o;
        o.x = f2bf((x[i][0] - mean) * rs * gg.x + bb.x);
        o.y = f2bf((x[i][1] - mean) * rs * gg.y + bb.y);
        o.z = f2bf((x[i][2] - mean) * rs * gg.z + bb.z);
        o.w = f2bf((x[i][3] - mean) * rs * gg.w + bb.w);
        *(ushort4*)(dst + row * 768 + v) = o;
    }
}

// ---------------------------------------------------------------------------
// proj32: out[M][32] = A[M][768](bf16) @ W[32][768](f32)^T + bias (plain).
// ---------------------------------------------------------------------------
__global__ __launch_bounds__(256) void proj32(
    const unsigned short* __restrict__ A, const float* __restrict__ W,
    const float* __restrict__ bias, unsigned short* __restrict__ out)
{
    __shared__ __align__(16) unsigned short lsW[32 * 776];
    __shared__ __align__(16) unsigned short lsA[128 * 40];
    const int t = threadIdx.x;

#pragma unroll
    for (int i = 0; i < 24; i++) {
        int fi = t + i * 256;
        int row = fi / 192;
        int c4  = fi % 192;
        float4 f = *(const float4*)(W + row * 768 + c4 * 4);
        ushort4 u;
        u.x = f2bf(f.x); u.y = f2bf(f.y); u.z = f2bf(f.z); u.w = f2bf(f.w);
        *(ushort4*)&lsW[row * 776 + c4 * 4] = u;
    }

    const size_t m0 = (size_t)blockIdx.x * 128;
    const int lane = t & 63, wave = t >> 6;
    const int wm = wave * 32;
    const int lr = lane & 15, kg = (lane >> 4) * 8;
    const int row_s = t >> 3, c4s = t & 7;

    f32x4 acc[2][2];
#pragma unroll
    for (int i = 0; i < 2; i++)
#pragma unroll
        for (int j = 0; j < 2; j++) acc[i][j] = (f32x4){0.f, 0.f, 0.f, 0.f};

    __syncthreads();

    for (int k0 = 0; k0 < 768; k0 += 32) {
#pragma unroll
        for (int i = 0; i < 4; i++) {
            int row = row_s + 32 * i;
            ushort4 v = *(const ushort4*)(A + (m0 + row) * 768 + k0 + c4s * 4);
            *(ushort4*)&lsA[row * 40 + c4s * 4] = v;
        }
        __syncthreads();
        short8 af[2], bw[2];
#pragma unroll
        for (int mi = 0; mi < 2; mi++)
            af[mi] = *(const short8*)&lsA[(wm + mi * 16 + lr) * 40 + kg];
#pragma unroll
        for (int ni = 0; ni < 2; ni++)
            bw[ni] = *(const short8*)&lsW[(ni * 16 + lr) * 776 + k0 + kg];
#pragma unroll
        for (int mi = 0; mi < 2; mi++)
#pragma unroll
            for (int ni = 0; ni < 2; ni++)
                acc[mi][ni] = __builtin_amdgcn_mfma_f32_16x16x32_bf16(
                    af[mi], bw[ni], acc[mi][ni], 0, 0, 0);
        __syncthreads();
    }

#pragma unroll
    for (int ni = 0; ni < 2; ni++) {
        int col = ni * 16 + lr;
        float bv = bias[col];
#pragma unroll
        for (int mi = 0; mi < 2; mi++) {
#pragma unroll
            for (int r = 0; r < 4; r++) {
                size_t grow = m0 + wm + mi * 16 + (lane >> 4) * 4 + r;
                out[grow * 32 + col] = f2bf(acc[mi][ni][r] + bv);
            }
        }
    }
}

// ---------------------------------------------------------------------------
// proj32k_stats: k = rs*(dot(x_raw, kwp) - mean*s_k) + c_k, with row stats
// computed in the K-loop.
// ---------------------------------------------------------------------------
__global__ __launch_bounds__(256) void proj32k_stats(
    const unsigned short* __restrict__ A, const float* __restrict__ W,
    const float* __restrict__ skv, const float* __restrict__ ckv,
    unsigned short* __restrict__ out, float2* __restrict__ st)
{
    __shared__ __align__(16) unsigned short lsW[32 * 776];
    __shared__ __align__(16) unsigned short lsA[128 * 40];
    __shared__ float2 lstat[128];
    const int t = threadIdx.x;

#pragma unroll
    for (int i = 0; i < 24; i++) {
        int fi = t + i * 256;
        int row = fi / 192;
        int c4  = fi % 192;
        float4 f = *(const float4*)(W + row * 768 + c4 * 4);
        ushort4 u;
        u.x = f2bf(f.x); u.y = f2bf(f.y); u.z = f2bf(f.z); u.w = f2bf(f.w);
        *(ushort4*)&lsW[row * 776 + c4 * 4] = u;
    }

    const size_t m0 = (size_t)blockIdx.x * 128;
    const int lane = t & 63, wave = t >> 6;
    const int wm = wave * 32;
    const int lr = lane & 15, kg = (lane >> 4) * 8;
    const int row_s = t >> 3, c4s = t & 7;

    f32x4 acc[2][2];
#pragma unroll
    for (int i = 0; i < 2; i++)
#pragma unroll
        for (int j = 0; j < 2; j++) acc[i][j] = (f32x4){0.f, 0.f, 0.f, 0.f};

    float s_[4] = {0.f, 0.f, 0.f, 0.f}, sq_[4] = {0.f, 0.f, 0.f, 0.f};

    __syncthreads();

    for (int k0 = 0; k0 < 768; k0 += 32) {
#pragma unroll
        for (int i = 0; i < 4; i++) {
            int row = row_s + 32 * i;
            ushort4 v = *(const ushort4*)(A + (m0 + row) * 768 + k0 + c4s * 4);
            *(ushort4*)&lsA[row * 40 + c4s * 4] = v;
            float x0 = bf2f(v.x), x1 = bf2f(v.y), x2 = bf2f(v.z), x3 = bf2f(v.w);
            s_[i]  += x0 + x1 + x2 + x3;
            sq_[i] += x0 * x0 + x1 * x1 + x2 * x2 + x3 * x3;
        }
        __syncthreads();
        short8 af[2], bw[2];
#pragma unroll
        for (int mi = 0; mi < 2; mi++)
            af[mi] = *(const short8*)&lsA[(wm + mi * 16 + lr) * 40 + kg];
#pragma unroll
        for (int ni = 0; ni < 2; ni++)
            bw[ni] = *(const short8*)&lsW[(ni * 16 + lr) * 776 + k0 + kg];
#pragma unroll
        for (int mi = 0; mi < 2; mi++)
#pragma unroll
            for (int ni = 0; ni < 2; ni++)
                acc[mi][ni] = __builtin_amdgcn_mfma_f32_16x16x32_bf16(
                    af[mi], bw[ni], acc[mi][ni], 0, 0, 0);
        __syncthreads();
    }

#pragma unroll
    for (int i = 0; i < 4; i++) {
#pragma unroll
        for (int off = 1; off < 8; off <<= 1) {
            s_[i]  += __shfl_xor(s_[i], off);
            sq_[i] += __shfl_xor(sq_[i], off);
        }
    }
    if (c4s == 0) {
#pragma unroll
        for (int i = 0; i < 4; i++) {
            int row = row_s + 32 * i;
            float mean = s_[i] * (1.f / 768.f);
            float var  = sq_[i] * (1.f / 768.f) - mean * mean;
            float2 sv = make_float2(mean, rsqrtf(var + 1e-5f));
            lstat[row] = sv;
            st[m0 + row] = sv;
        }
    }
    __syncthreads();

#pragma unroll
    for (int ni = 0; ni < 2; ni++) {
        int col = ni * 16 + lr;
        float sk = skv[col], ck = ckv[col];
#pragma unroll
        for (int mi = 0; mi < 2; mi++) {
#pragma unroll
            for (int r = 0; r < 4; r++) {
                int lrow = wm + mi * 16 + (lane >> 4) * 4 + r;
                float2 s2 = lstat[lrow];
                out[(m0 + lrow) * 32 + col] =
                    f2bf(s2.y * (acc[mi][ni][r] - s2.x * sk) + ck);
            }
        }
    }
}

// ---------------------------------------------------------------------------
// Attention on RAW aligned values with LN folded in.  One wave per token.
// ---------------------------------------------------------------------------
__global__ __launch_bounds__(256) void attn2(
    const unsigned short* __restrict__ qb, const unsigned short* __restrict__ kb,
    const unsigned short* __restrict__ kv, const float2* __restrict__ st,
    const float* __restrict__ gv, const float* __restrict__ bvv,
    unsigned short* __restrict__ oh)
{
    __shared__ float lat[4][4][13];
    __shared__ float latc[4][4];
    const int t = threadIdx.x, lane = t & 63, wave = t >> 6;
    const size_t m = (size_t)blockIdx.x * 4 + wave;

    if (lane < 32) {
        int j = lane;
        float qv = bf2f(qb[m * 32 + j]);
        float p[13];
#pragma unroll
        for (int l = 0; l < 13; l++)
            p[l] = qv * bf2f(kb[(m * 13 + l) * 32 + j]);
#pragma unroll
        for (int off = 1; off < 8; off <<= 1)
#pragma unroll
            for (int l = 0; l < 13; l++) p[l] += __shfl_xor(p[l], off);

        const float sc = 0.17677669529663687f; // 1 / (sqrt(8) * 2)
        float mx = -1e30f;
#pragma unroll
        for (int l = 0; l < 13; l++) { p[l] *= sc; mx = fmaxf(mx, p[l]); }
        float se = 0.f;
#pragma unroll
        for (int l = 0; l < 13; l++) { p[l] = __expf(p[l] - mx); se += p[l]; }
        float inv = 1.f / se;
        if ((j & 7) == 0) {
            int h = j >> 3;
            float corr = 0.f;
#pragma unroll
            for (int l = 0; l < 13; l++) {
                float2 s_ = st[m * 13 + l];
                float wl = p[l] * inv * s_.y;
                lat[wave][h][l] = wl;
                corr += wl * s_.x;
            }
            latc[wave][h] = corr;
        }
    }
    __syncthreads();

    f32x4 g4v[3], b4[3];
#pragma unroll
    for (int i = 0; i < 3; i++) {
        g4v[i] = *(const f32x4*)(gv + i * 256 + lane * 4);
        b4[i] = *(const f32x4*)(bvv + i * 256 + lane * 4);
    }

    float acc[4][3][4];
#pragma unroll
    for (int h = 0; h < 4; h++)
#pragma unroll
        for (int i = 0; i < 3; i++)
#pragma unroll
            for (int e = 0; e < 4; e++) acc[h][i][e] = 0.f;

    for (int l = 0; l < 13; l++) {
        float al[4];
#pragma unroll
        for (int h = 0; h < 4; h++) al[h] = lat[wave][h][l];
#pragma unroll
        for (int i = 0; i < 3; i++) {
            ushort4 u = *(const ushort4*)(kv + (m * 13 + l) * 768 + i * 256 + lane * 4);
            float xv[4] = {bf2f(u.x), bf2f(u.y), bf2f(u.z), bf2f(u.w)};
#pragma unroll
            for (int h = 0; h < 4; h++)
#pragma unroll
                for (int e = 0; e < 4; e++) acc[h][i][e] += al[h] * xv[e];
        }
    }
#pragma unroll
    for (int h = 0; h < 4; h++) {
        float ch = latc[wave][h];
#pragma unroll
        for (int i = 0; i < 3; i++) {
            ushort4 o;
            o.x = f2bf(g4v[i][0] * (acc[h][i][0] - ch) + b4[i][0]);
            o.y = f2bf(g4v[i][1] * (acc[h][i][1] - ch) + b4[i][1]);
            o.z = f2bf(g4v[i][2] * (acc[h][i][2] - ch) + b4[i][2]);
            o.w = f2bf(g4v[i][3] * (acc[h][i][3] - ch) + b4[i][3]);
            *(ushort4*)(oh + m * 3072 + h * 768 + i * 256 + lane * 4) = o;
        }
    }
}

// ---------------------------------------------------------------------------
extern "C" void kernel_launch(void* const* d_in, const int* in_sizes, int n_in,
                              void* d_out, int out_size, void* d_ws, size_t ws_size,
                              hipStream_t stream) {
    const float* base  = (const float*)d_in[0];
    const float* reps  = (const float*)d_in[1];
    const float* aw    = (const float*)d_in[2];
    const float* ab    = (const float*)d_in[3];
    const float* qg    = (const float*)d_in[4];
    const float* qbeta = (const float*)d_in[5];
    const float* kvg   = (const float*)d_in[6];
    const float* kvb   = (const float*)d_in[7];
    const float* qw    = (const float*)d_in[8];
    const float* qbias = (const float*)d_in[9];
    const float* kw    = (const float*)d_in[10];
    const float* kbias = (const float*)d_in[11];
    const float* ow    = (const float*)d_in[12];
    const float* obias = (const float*)d_in[13];
    float* out = (float*)d_out;

    float2* stats = (float2*)d_ws;                              // [MROWS]
    float* kwp = (float*)(stats + MROWS);                       // [32][768]
    float* skv = kwp + 32 * 768;                                // [32]
    float* ckv = skv + 32;                                      // [32]
    unsigned short* aligned = (unsigned short*)(ckv + 32);      // [MROWS][768]
    unsigned short* UNION = aligned + (size_t)MROWS * 768;      // awb -> Qn -> oh
    unsigned short* kbuf = UNION + (size_t)MTOK * 3072;         // [MROWS][32]
    unsigned short* qbuf = kbuf + (size_t)MROWS * 32;           // [MTOK][32]
    unsigned short* owb  = qbuf + (size_t)MTOK * 32;            // [768][3072]

    unsigned short* awb = UNION;

    // 0. weight conversions + LN folding precompute
    {
        long n = (long)NL * 768 * 768;
        conv_f32_bf16<<<(int)(n / 8 / 256), 256, 0, stream>>>(aw, awb, n);
        long n2 = (long)768 * 3072;
        conv_f32_bf16<<<(int)(n2 / 8 / 256), 256, 0, stream>>>(ow, owb, n2);
        wtrans<<<32, 256, 0, stream>>>(kw, kvg, kvb, kbias, kwp, skv, ckv);
    }

    // 1. aligner GEMM: 256^2, chunk-major LDS, 2 buffers -> 2 blocks/CU
    gemm_f32a<<<1248, 512, 0, stream>>>(
        reps, awb, ab, aligned,
        (long)MTOK * 768, (long)768 * 768, 768,
        768L, (long)NL * 768);

    // 2. k projection + fused row stats
    proj32k_stats<<<MROWS / 128, 256, 0, stream>>>(
        aligned, kwp, skv, ckv, kbuf, stats);

    // 3. q side: LN(base) -> Qn, then proj32 (awb dead, reuse UNION)
    unsigned short* Qn = UNION;
    ln_rows_f32<<<MTOK / 4, 256, 0, stream>>>(base, Qn, qg, qbeta);
    proj32<<<MTOK / 128, 256, 0, stream>>>(Qn, qw, qbias, qbuf);

    // 4. attention on raw aligned (Qn dead, reuse UNION for oh)
    unsigned short* oh = UNION;
    attn2<<<MTOK / 4, 256, 0, stream>>>(qbuf, kbuf, aligned, stats, kvg, kvb, oh);

    // 5. out = out_heads @ out_w^T + out_b (64x128 tiles, 768 blocks)
    gemm_bf16_nt<<<768, 256, 0, stream>>>(oh, owb, obias, out, 3072, 768L);
}

// Round 16
// 433.671 us; speedup vs baseline: 5.4960x; 5.4960x over previous
//
#include <hip/hip_runtime.h>
#include <stdint.h>

#define NB 8
#define NT 1024
#define ND 768
#define NV 768
#define NL 13
#define MTOK (NB*NT)          // 8192
#define MROWS (MTOK*NL)       // 106496

typedef __attribute__((ext_vector_type(8))) short short8;
typedef __attribute__((ext_vector_type(4))) float f32x4;

__device__ __forceinline__ unsigned short f2bf(float f) {
    union { float f; unsigned u; } v; v.f = f;
    unsigned r = v.u + 0x7FFFu + ((v.u >> 16) & 1u);
    return (unsigned short)(r >> 16);
}
__device__ __forceinline__ float bf2f(unsigned short u) {
    union { unsigned u; float f; } v; v.u = ((unsigned)u) << 16;
    return v.f;
}
__device__ __forceinline__ unsigned cvtpk(float lo, float hi) {
    unsigned r;
    asm("v_cvt_pk_bf16_f32 %0, %1, %2" : "=v"(r) : "v"(lo), "v"(hi));
    return r;
}
__device__ __forceinline__ void gload16(const void* g, void* l) {
    __builtin_amdgcn_global_load_lds(
        (const __attribute__((address_space(1))) unsigned int*)g,
        (__attribute__((address_space(3))) unsigned int*)l, 16, 0, 0);
}

#define PHB { __builtin_amdgcn_s_barrier(); __builtin_amdgcn_sched_barrier(0); }

// ---------------------------------------------------------------------------
// fp32 -> bf16 bulk convert (weights only)
// ---------------------------------------------------------------------------
__global__ __launch_bounds__(256) void conv_f32_bf16(
    const float* __restrict__ s, unsigned short* __restrict__ d, long n)
{
    long i = ((long)blockIdx.x * 256 + threadIdx.x) * 8;
    long st = (long)gridDim.x * 2048;
    for (; i < n; i += st) {
        float4 a = *(const float4*)(s + i);
        float4 b = *(const float4*)(s + i + 4);
        ushort4 u0, u1;
        u0.x = f2bf(a.x); u0.y = f2bf(a.y); u0.z = f2bf(a.z); u0.w = f2bf(a.w);
        u1.x = f2bf(b.x); u1.y = f2bf(b.y); u1.z = f2bf(b.z); u1.w = f2bf(b.w);
        *(ushort4*)(d + i)     = u0;
        *(ushort4*)(d + i + 4) = u1;
    }
}

// ---------------------------------------------------------------------------
// GEMM1: C(bf16) = A(fp32) * B(bf16)^T + bias.  K=768, BK=32, 24 K-tiles.
// 256x256 tile, 8 waves (2M x 4N), per-wave 128x64.
// R14 structure with TWO LDS buffers (64 KB) and launch_bounds(512,2):
// VGPR stays ~124 (<=128) so 2 blocks/CU co-reside via BOTH the LDS and
// VGPR limits -> inter-block TLP covers per-tile drain+barrier (m114).
// (R15's launch_bounds(512,4) wrongly capped VGPR at 64 -> spills.)
// ---------------------------------------------------------------------------
__global__ __launch_bounds__(512, 2) void gemm_f32a(
    const float* __restrict__ A, const unsigned short* __restrict__ B,
    const float* __restrict__ biasBase, unsigned short* __restrict__ C,
    long aLS, long bLS, int biasLS, long cLayerOff, long cRowStride)
{
    __shared__ __align__(16) unsigned short lsA[2][4 * 256 * 8];  // 16KB/buf
    __shared__ __align__(16) unsigned short lsB[2][4 * 256 * 8];

    const int bid = blockIdx.x;
    const int xcd = bid & 7, slot = bid >> 3;        // 156 slots per XCD
    const int grp = xcd * 52 + slot / 3;             // 0..415
    const int nx  = slot % 3;
    const int l   = grp >> 5;                        // layer 0..12
    const long m0 = (long)(grp & 31) * 256;
    const long n0 = (long)nx * 256;

    const int t = threadIdx.x, lane = t & 63, wave = t >> 6;

    const float* Ab = A + (size_t)l * aLS;
    const unsigned short* Bb = B + (size_t)l * bLS;
    const float* bias = biasBase + (size_t)l * biasLS;

    // staging: thread covers row t>>1 (0..255), k-half t&1 (16 elems)
    const int sRow  = t >> 1;
    const int sHalf = t & 1;
    const float* aSrc = Ab + (m0 + sRow) * (size_t)768 + sHalf * 16;
    const unsigned short* bSrc = Bb + (n0 + sRow) * (size_t)768 + sHalf * 16;

    const int wm = (wave >> 2) * 128;    // 2 M-wave groups
    const int wn = (wave & 3) * 64;      // 4 N-wave groups
    const int lr = lane & 15;
    const int g4 = lane >> 4;

    f32x4 acc[8][4];
#pragma unroll
    for (int i = 0; i < 8; i++)
#pragma unroll
        for (int j = 0; j < 4; j++) acc[i][j] = (f32x4){0.f, 0.f, 0.f, 0.f};

    f32x4 ra0[4], ra1[4];
    short8 rb0[2], rb1[2];

#define LOADA(R, K0) { _Pragma("unroll") \
    for (int i_ = 0; i_ < 4; i_++) (R)[i_] = *(const f32x4*)(aSrc + (K0) + i_ * 4); }
#define LOADB(R, K0) { _Pragma("unroll") \
    for (int j_ = 0; j_ < 2; j_++) (R)[j_] = *(const short8*)(bSrc + (K0) + j_ * 8); }
#define WRITEA(R, BUF) { unsigned short* la_ = lsA[BUF]; \
    uint4 w0_, w1_; \
    w0_.x = cvtpk((R)[0][0], (R)[0][1]); w0_.y = cvtpk((R)[0][2], (R)[0][3]); \
    w0_.z = cvtpk((R)[1][0], (R)[1][1]); w0_.w = cvtpk((R)[1][2], (R)[1][3]); \
    w1_.x = cvtpk((R)[2][0], (R)[2][1]); w1_.y = cvtpk((R)[2][2], (R)[2][3]); \
    w1_.z = cvtpk((R)[3][0], (R)[3][1]); w1_.w = cvtpk((R)[3][2], (R)[3][3]); \
    *(uint4*)&la_[(2 * sHalf + 0) * 2048 + sRow * 8] = w0_; \
    *(uint4*)&la_[(2 * sHalf + 1) * 2048 + sRow * 8] = w1_; }
#define WRITEB(R, BUF) { unsigned short* lb_ = lsB[BUF]; \
    *(short8*)&lb_[(2 * sHalf + 0) * 2048 + sRow * 8] = (R)[0]; \
    *(short8*)&lb_[(2 * sHalf + 1) * 2048 + sRow * 8] = (R)[1]; }

    // Merged single-window tile: loads, frag reads, 32 MFMA, writes, 1 barrier.
#define TILE(KS, RLA, RLB, RWA, RWB, DOL, DOW) { \
    const unsigned short* pa_ = lsA[(KS) & 1]; \
    const unsigned short* pb_ = lsB[(KS) & 1]; \
    if (DOL) { LOADA(RLA, ((KS) + 2) * 32); LOADB(RLB, ((KS) + 2) * 32); } \
    short8 bv_[4], af_[8]; \
    _Pragma("unroll") \
    for (int ni_ = 0; ni_ < 4; ni_++) \
        bv_[ni_] = *(const short8*)&pb_[g4 * 2048 + (wn + ni_ * 16 + lr) * 8]; \
    _Pragma("unroll") \
    for (int mi_ = 0; mi_ < 8; mi_++) \
        af_[mi_] = *(const short8*)&pa_[g4 * 2048 + (wm + mi_ * 16 + lr) * 8]; \
    __builtin_amdgcn_s_setprio(1); \
    _Pragma("unroll") \
    for (int mi_ = 0; mi_ < 8; mi_++) \
        _Pragma("unroll") \
        for (int ni_ = 0; ni_ < 4; ni_++) \
            acc[mi_][ni_] = __builtin_amdgcn_mfma_f32_16x16x32_bf16( \
                af_[mi_], bv_[ni_], acc[mi_][ni_], 0, 0, 0); \
    __builtin_amdgcn_s_setprio(0); \
    if (DOW) { WRITEA(RWA, ((KS) + 1) & 1); WRITEB(RWB, ((KS) + 1) & 1); } \
    asm volatile("s_waitcnt lgkmcnt(0)" ::: "memory"); PHB; }

    // Prologue: tile0 -> regs -> LDS buf0; tile1 -> regs (pending, written
    // at tile0's body).  Compiler inserts the vmcnt waits for reg reads.
    LOADA(ra0, 0);  LOADB(rb0, 0);
    LOADA(ra1, 32); LOADB(rb1, 32);
    WRITEA(ra0, 0); WRITEB(rb0, 0);
    __syncthreads();

    // Steady: tile t computes buf[t&1]; loads tile t+2 into regs[t&1];
    // writes tile t+1 (regs[(t+1)&1]) into buf[(t+1)&1].
    for (int tp = 0; tp < 20; tp += 2) {
        TILE(tp,     ra0, rb0, ra1, rb1, 1, 1);
        TILE(tp + 1, ra1, rb1, ra0, rb0, 1, 1);
    }
    TILE(20, ra0, rb0, ra1, rb1, 1, 1);
    TILE(21, ra1, rb1, ra0, rb0, 1, 1);
    TILE(22, ra0, rb0, ra1, rb1, 0, 1);   // writes tile 23 (loaded at t=21)
    TILE(23, ra1, rb1, ra0, rb0, 0, 0);

#undef TILE
#undef WRITEB
#undef WRITEA
#undef LOADB
#undef LOADA

#pragma unroll
    for (int ni = 0; ni < 4; ni++) {
        long col = n0 + wn + ni * 16 + lr;
        float bvs = bias[col];
#pragma unroll
        for (int mi = 0; mi < 8; mi++) {
#pragma unroll
            for (int r = 0; r < 4; r++) {
                long grow = m0 + wm + mi * 16 + g4 * 4 + r;
                size_t coff = (size_t)grow * cRowStride + (size_t)l * cLayerOff + col;
                C[coff] = f2bf(acc[mi][ni][r] + bvs);
            }
        }
    }
}

// ---------------------------------------------------------------------------
// GEMM2: C(f32) = A(bf16) * B(bf16)^T + bias.  64x128 tile, BK=32, gload
// staging + XOR swizzle (R6/R10-verified), grid 768 = 8 x 16 x 6.
// ---------------------------------------------------------------------------
__global__ __launch_bounds__(256) void gemm_bf16_nt(
    const unsigned short* __restrict__ A, const unsigned short* __restrict__ B,
    const float* __restrict__ bias, float* __restrict__ C,
    int K, long cRowStride)
{
    __shared__ __align__(16) unsigned short lsA[2][64 * 32];
    __shared__ __align__(16) unsigned short lsB[2][128 * 32];

    const int bid = blockIdx.x;
    const int xcd = bid & 7, slot = bid >> 3;        // 96 slots per XCD
    const int grp = xcd * 16 + slot / 6;             // 0..127 m-blocks
    const int nx  = slot % 6;
    const long m0 = (long)grp * 64;
    const long n0 = (long)nx * 128;

    const int t = threadIdx.x, lane = t & 63, wave = t >> 6;

    const int srow = wave * 16 + (lane >> 2);        // 0..63
    const int schk = (lane & 3) ^ ((lane >> 3) & 3);
    const int dS   = wave * 1024 + lane * 16;

    const int wm = (wave >> 1) * 32;
    const int wn = (wave & 1) * 64;
    const int lr = lane & 15;
    const int g4 = lane >> 4;
    const int kg = g4 * 8;
    const int swz = ((lr >> 1) & 3) * 8;

    const unsigned short* aSp  = A + (m0 + srow) * (size_t)K + schk * 8;
    const unsigned short* bSp0 = B + (n0 + srow) * (size_t)K + schk * 8;
    const unsigned short* bSp1 = B + (n0 + 64 + srow) * (size_t)K + schk * 8;

    f32x4 acc[2][4];
#pragma unroll
    for (int i = 0; i < 2; i++)
#pragma unroll
        for (int j = 0; j < 4; j++) acc[i][j] = (f32x4){0.f, 0.f, 0.f, 0.f};

    auto STAGE = [&](int buf, int k0) {
        char* la = (char*)lsA[buf];
        char* lb = (char*)lsB[buf];
        gload16(aSp + k0, la + dS);
        gload16(bSp0 + k0, lb + dS);
        gload16(bSp1 + k0, lb + 4096 + dS);
    };
    auto COMP = [&](int buf) {
        short8 af[2], bv[4];
        const unsigned short* pa = lsA[buf];
        const unsigned short* pb = lsB[buf];
#pragma unroll
        for (int mi = 0; mi < 2; mi++)
            af[mi] = *(const short8*)&pa[(wm + mi * 16 + lr) * 32 + (kg ^ swz)];
#pragma unroll
        for (int ni = 0; ni < 4; ni++)
            bv[ni] = *(const short8*)&pb[(wn + ni * 16 + lr) * 32 + (kg ^ swz)];
#pragma unroll
        for (int mi = 0; mi < 2; mi++)
#pragma unroll
            for (int ni = 0; ni < 4; ni++)
                acc[mi][ni] = __builtin_amdgcn_mfma_f32_16x16x32_bf16(
                    af[mi], bv[ni], acc[mi][ni], 0, 0, 0);
    };

    STAGE(0, 0);
    __syncthreads();
    int cur = 0;
    const int nst = K >> 5;
    for (int ks = 1; ks < nst; ks++) {
        STAGE(cur ^ 1, ks * 32);
        COMP(cur);
        __syncthreads();
        cur ^= 1;
    }
    COMP(cur);

#pragma unroll
    for (int ni = 0; ni < 4; ni++) {
        long col = n0 + wn + ni * 16 + lr;
        float bvs = bias[col];
#pragma unroll
        for (int mi = 0; mi < 2; mi++) {
#pragma unroll
            for (int r = 0; r < 4; r++) {
                long grow = m0 + wm + mi * 16 + g4 * 4 + r;
                C[(size_t)grow * cRowStride + col] = acc[mi][ni][r] + bvs;
            }
        }
    }
}

// ---------------------------------------------------------------------------
// Fold kvln gamma into k_w; compute s_k = sum(kw*g), c_k = kw.b + k_bias.
// ---------------------------------------------------------------------------
__global__ __launch_bounds__(256) void wtrans(
    const float* __restrict__ kw, const float* __restrict__ kvg,
    const float* __restrict__ kvb, const float* __restrict__ kbias,
    float* __restrict__ kwp, float* __restrict__ skv, float* __restrict__ ckv)
{
    __shared__ float red[8];
    const int q = blockIdx.x, t = threadIdx.x;
    const int lane = t & 63, wave = t >> 6;
    float s = 0.f, c = 0.f;
    for (int v = t; v < 768; v += 256) {
        float w = kw[q * 768 + v];
        float wp = w * kvg[v];
        kwp[q * 768 + v] = wp;
        s += wp;
        c += w * kvb[v];
    }
#pragma unroll
    for (int off = 1; off < 64; off <<= 1) {
        s += __shfl_xor(s, off);
        c += __shfl_xor(c, off);
    }
    if (lane == 0) { red[wave] = s; red[4 + wave] = c; }
    __syncthreads();
    if (t == 0) {
        skv[q] = red[0] + red[1] + red[2] + red[3];
        ckv[q] = red[4] + red[5] + red[6] + red[7] + kbias[q];
    }
}

// ---------------------------------------------------------------------------
// LayerNorm rows of 768 (fp32 src) -> bf16.  Q side only.
// ---------------------------------------------------------------------------
__global__ __launch_bounds__(256) void ln_rows_f32(
    const float* __restrict__ src, unsigned short* __restrict__ dst,
    const float* __restrict__ gam, const float* __restrict__ bet)
{
    const int lane = threadIdx.x & 63;
    const int wave = threadIdx.x >> 6;
    const size_t row = (size_t)blockIdx.x * 4 + wave;

    float x[3][4];
    float s = 0.f, sq = 0.f;
#pragma unroll
    for (int i = 0; i < 3; i++) {
        int v = i * 256 + lane * 4;
        float4 f = *(const float4*)(src + row * 768 + v);
        x[i][0] = f.x; x[i][1] = f.y; x[i][2] = f.z; x[i][3] = f.w;
#pragma unroll
        for (int e = 0; e < 4; e++) { s += x[i][e]; sq += x[i][e] * x[i][e]; }
    }
#pragma unroll
    for (int off = 1; off < 64; off <<= 1) {
        s  += __shfl_xor(s, off);
        sq += __shfl_xor(sq, off);
    }
    float mean = s * (1.f / 768.f);
    float var  = sq * (1.f / 768.f) - mean * mean;
    float rs   = rsqrtf(var + 1e-5f);
#pragma unroll
    for (int i = 0; i < 3; i++) {
        int v = i * 256 + lane * 4;
        float4 gg = *(const float4*)(gam + v);
        float4 bb = *(const float4*)(bet + v);
        ushort4 o;
        o.x = f2bf((x[i][0] - mean) * rs * gg.x + bb.x);
        o.y = f2bf((x[i][1] - mean) * rs * gg.y + bb.y);
        o.z = f2bf((x[i][2] - mean) * rs * gg.z + bb.z);
        o.w = f2bf((x[i][3] - mean) * rs * gg.w + bb.w);
        *(ushort4*)(dst + row * 768 + v) = o;
    }
}

// ---------------------------------------------------------------------------
// proj32: out[M][32] = A[M][768](bf16) @ W[32][768](f32)^T + bias (plain).
// ---------------------------------------------------------------------------
__global__ __launch_bounds__(256) void proj32(
    const unsigned short* __restrict__ A, const float* __restrict__ W,
    const float* __restrict__ bias, unsigned short* __restrict__ out)
{
    __shared__ __align__(16) unsigned short lsW[32 * 776];
    __shared__ __align__(16) unsigned short lsA[128 * 40];
    const int t = threadIdx.x;

#pragma unroll
    for (int i = 0; i < 24; i++) {
        int fi = t + i * 256;
        int row = fi / 192;
        int c4  = fi % 192;
        float4 f = *(const float4*)(W + row * 768 + c4 * 4);
        ushort4 u;
        u.x = f2bf(f.x); u.y = f2bf(f.y); u.z = f2bf(f.z); u.w = f2bf(f.w);
        *(ushort4*)&lsW[row * 776 + c4 * 4] = u;
    }

    const size_t m0 = (size_t)blockIdx.x * 128;
    const int lane = t & 63, wave = t >> 6;
    const int wm = wave * 32;
    const int lr = lane & 15, kg = (lane >> 4) * 8;
    const int row_s = t >> 3, c4s = t & 7;

    f32x4 acc[2][2];
#pragma unroll
    for (int i = 0; i < 2; i++)
#pragma unroll
        for (int j = 0; j < 2; j++) acc[i][j] = (f32x4){0.f, 0.f, 0.f, 0.f};

    __syncthreads();

    for (int k0 = 0; k0 < 768; k0 += 32) {
#pragma unroll
        for (int i = 0; i < 4; i++) {
            int row = row_s + 32 * i;
            ushort4 v = *(const ushort4*)(A + (m0 + row) * 768 + k0 + c4s * 4);
            *(ushort4*)&lsA[row * 40 + c4s * 4] = v;
        }
        __syncthreads();
        short8 af[2], bw[2];
#pragma unroll
        for (int mi = 0; mi < 2; mi++)
            af[mi] = *(const short8*)&lsA[(wm + mi * 16 + lr) * 40 + kg];
#pragma unroll
        for (int ni = 0; ni < 2; ni++)
            bw[ni] = *(const short8*)&lsW[(ni * 16 + lr) * 776 + k0 + kg];
#pragma unroll
        for (int mi = 0; mi < 2; mi++)
#pragma unroll
            for (int ni = 0; ni < 2; ni++)
                acc[mi][ni] = __builtin_amdgcn_mfma_f32_16x16x32_bf16(
                    af[mi], bw[ni], acc[mi][ni], 0, 0, 0);
        __syncthreads();
    }

#pragma unroll
    for (int ni = 0; ni < 2; ni++) {
        int col = ni * 16 + lr;
        float bv = bias[col];
#pragma unroll
        for (int mi = 0; mi < 2; mi++) {
#pragma unroll
            for (int r = 0; r < 4; r++) {
                size_t grow = m0 + wm + mi * 16 + (lane >> 4) * 4 + r;
                out[grow * 32 + col] = f2bf(acc[mi][ni][r] + bv);
            }
        }
    }
}

// ---------------------------------------------------------------------------
// proj32k_stats: k = rs*(dot(x_raw, kwp) - mean*s_k) + c_k, with row stats
// computed in the K-loop.
// ---------------------------------------------------------------------------
__global__ __launch_bounds__(256) void proj32k_stats(
    const unsigned short* __restrict__ A, const float* __restrict__ W,
    const float* __restrict__ skv, const float* __restrict__ ckv,
    unsigned short* __restrict__ out, float2* __restrict__ st)
{
    __shared__ __align__(16) unsigned short lsW[32 * 776];
    __shared__ __align__(16) unsigned short lsA[128 * 40];
    __shared__ float2 lstat[128];
    const int t = threadIdx.x;

#pragma unroll
    for (int i = 0; i < 24; i++) {
        int fi = t + i * 256;
        int row = fi / 192;
        int c4  = fi % 192;
        float4 f = *(const float4*)(W + row * 768 + c4 * 4);
        ushort4 u;
        u.x = f2bf(f.x); u.y = f2bf(f.y); u.z = f2bf(f.z); u.w = f2bf(f.w);
        *(ushort4*)&lsW[row * 776 + c4 * 4] = u;
    }

    const size_t m0 = (size_t)blockIdx.x * 128;
    const int lane = t & 63, wave = t >> 6;
    const int wm = wave * 32;
    const int lr = lane & 15, kg = (lane >> 4) * 8;
    const int row_s = t >> 3, c4s = t & 7;

    f32x4 acc[2][2];
#pragma unroll
    for (int i = 0; i < 2; i++)
#pragma unroll
        for (int j = 0; j < 2; j++) acc[i][j] = (f32x4){0.f, 0.f, 0.f, 0.f};

    float s_[4] = {0.f, 0.f, 0.f, 0.f}, sq_[4] = {0.f, 0.f, 0.f, 0.f};

    __syncthreads();

    for (int k0 = 0; k0 < 768; k0 += 32) {
#pragma unroll
        for (int i = 0; i < 4; i++) {
            int row = row_s + 32 * i;
            ushort4 v = *(const ushort4*)(A + (m0 + row) * 768 + k0 + c4s * 4);
            *(ushort4*)&lsA[row * 40 + c4s * 4] = v;
            float x0 = bf2f(v.x), x1 = bf2f(v.y), x2 = bf2f(v.z), x3 = bf2f(v.w);
            s_[i]  += x0 + x1 + x2 + x3;
            sq_[i] += x0 * x0 + x1 * x1 + x2 * x2 + x3 * x3;
        }
        __syncthreads();
        short8 af[2], bw[2];
#pragma unroll
        for (int mi = 0; mi < 2; mi++)
            af[mi] = *(const short8*)&lsA[(wm + mi * 16 + lr) * 40 + kg];
#pragma unroll
        for (int ni = 0; ni < 2; ni++)
            bw[ni] = *(const short8*)&lsW[(ni * 16 + lr) * 776 + k0 + kg];
#pragma unroll
        for (int mi = 0; mi < 2; mi++)
#pragma unroll
            for (int ni = 0; ni < 2; ni++)
                acc[mi][ni] = __builtin_amdgcn_mfma_f32_16x16x32_bf16(
                    af[mi], bw[ni], acc[mi][ni], 0, 0, 0);
        __syncthreads();
    }

#pragma unroll
    for (int i = 0; i < 4; i++) {
#pragma unroll
        for (int off = 1; off < 8; off <<= 1) {
            s_[i]  += __shfl_xor(s_[i], off);
            sq_[i] += __shfl_xor(sq_[i], off);
        }
    }
    if (c4s == 0) {
#pragma unroll
        for (int i = 0; i < 4; i++) {
            int row = row_s + 32 * i;
            float mean = s_[i] * (1.f / 768.f);
            float var  = sq_[i] * (1.f / 768.f) - mean * mean;
            float2 sv = make_float2(mean, rsqrtf(var + 1e-5f));
            lstat[row] = sv;
            st[m0 + row] = sv;
        }
    }
    __syncthreads();

#pragma unroll
    for (int ni = 0; ni < 2; ni++) {
        int col = ni * 16 + lr;
        float sk = skv[col], ck = ckv[col];
#pragma unroll
        for (int mi = 0; mi < 2; mi++) {
#pragma unroll
            for (int r = 0; r < 4; r++) {
                int lrow = wm + mi * 16 + (lane >> 4) * 4 + r;
                float2 s2 = lstat[lrow];
                out[(m0 + lrow) * 32 + col] =
                    f2bf(s2.y * (acc[mi][ni][r] - s2.x * sk) + ck);
            }
        }
    }
}

// ---------------------------------------------------------------------------
// Attention on RAW aligned values with LN folded in.  One wave per token.
// ---------------------------------------------------------------------------
__global__ __launch_bounds__(256) void attn2(
    const unsigned short* __restrict__ qb, const unsigned short* __restrict__ kb,
    const unsigned short* __restrict__ kv, const float2* __restrict__ st,
    const float* __restrict__ gv, const float* __restrict__ bvv,
    unsigned short* __restrict__ oh)
{
    __shared__ float lat[4][4][13];
    __shared__ float latc[4][4];
    const int t = threadIdx.x, lane = t & 63, wave = t >> 6;
    const size_t m = (size_t)blockIdx.x * 4 + wave;

    if (lane < 32) {
        int j = lane;
        float qv = bf2f(qb[m * 32 + j]);
        float p[13];
#pragma unroll
        for (int l = 0; l < 13; l++)
            p[l] = qv * bf2f(kb[(m * 13 + l) * 32 + j]);
#pragma unroll
        for (int off = 1; off < 8; off <<= 1)
#pragma unroll
            for (int l = 0; l < 13; l++) p[l] += __shfl_xor(p[l], off);

        const float sc = 0.17677669529663687f; // 1 / (sqrt(8) * 2)
        float mx = -1e30f;
#pragma unroll
        for (int l = 0; l < 13; l++) { p[l] *= sc; mx = fmaxf(mx, p[l]); }
        float se = 0.f;
#pragma unroll
        for (int l = 0; l < 13; l++) { p[l] = __expf(p[l] - mx); se += p[l]; }
        float inv = 1.f / se;
        if ((j & 7) == 0) {
            int h = j >> 3;
            float corr = 0.f;
#pragma unroll
            for (int l = 0; l < 13; l++) {
                float2 s_ = st[m * 13 + l];
                float wl = p[l] * inv * s_.y;
                lat[wave][h][l] = wl;
                corr += wl * s_.x;
            }
            latc[wave][h] = corr;
        }
    }
    __syncthreads();

    f32x4 g4v[3], b4[3];
#pragma unroll
    for (int i = 0; i < 3; i++) {
        g4v[i] = *(const f32x4*)(gv + i * 256 + lane * 4);
        b4[i] = *(const f32x4*)(bvv + i * 256 + lane * 4);
    }

    float acc[4][3][4];
#pragma unroll
    for (int h = 0; h < 4; h++)
#pragma unroll
        for (int i = 0; i < 3; i++)
#pragma unroll
            for (int e = 0; e < 4; e++) acc[h][i][e] = 0.f;

    for (int l = 0; l < 13; l++) {
        float al[4];
#pragma unroll
        for (int h = 0; h < 4; h++) al[h] = lat[wave][h][l];
#pragma unroll
        for (int i = 0; i < 3; i++) {
            ushort4 u = *(const ushort4*)(kv + (m * 13 + l) * 768 + i * 256 + lane * 4);
            float xv[4] = {bf2f(u.x), bf2f(u.y), bf2f(u.z), bf2f(u.w)};
#pragma unroll
            for (int h = 0; h < 4; h++)
#pragma unroll
                for (int e = 0; e < 4; e++) acc[h][i][e] += al[h] * xv[e];
        }
    }
#pragma unroll
    for (int h = 0; h < 4; h++) {
        float ch = latc[wave][h];
#pragma unroll
        for (int i = 0; i < 3; i++) {
            ushort4 o;
            o.x = f2bf(g4v[i][0] * (acc[h][i][0] - ch) + b4[i][0]);
            o.y = f2bf(g4v[i][1] * (acc[h][i][1] - ch) + b4[i][1]);
            o.z = f2bf(g4v[i][2] * (acc[h][i][2] - ch) + b4[i][2]);
            o.w = f2bf(g4v[i][3] * (acc[h][i][3] - ch) + b4[i][3]);
            *(ushort4*)(oh + m * 3072 + h * 768 + i * 256 + lane * 4) = o;
        }
    }
}

// ---------------------------------------------------------------------------
extern "C" void kernel_launch(void* const* d_in, const int* in_sizes, int n_in,
                              void* d_out, int out_size, void* d_ws, size_t ws_size,
                              hipStream_t stream) {
    const float* base  = (const float*)d_in[0];
    const float* reps  = (const float*)d_in[1];
    const float* aw    = (const float*)d_in[2];
    const float* ab    = (const float*)d_in[3];
    const float* qg    = (const float*)d_in[4];
    const float* qbeta = (const float*)d_in[5];
    const float* kvg   = (const float*)d_in[6];
    const float* kvb   = (const float*)d_in[7];
    const float* qw    = (const float*)d_in[8];
    const float* qbias = (const float*)d_in[9];
    const float* kw    = (const float*)d_in[10];
    const float* kbias = (const float*)d_in[11];
    const float* ow    = (const float*)d_in[12];
    const float* obias = (const float*)d_in[13];
    float* out = (float*)d_out;

    float2* stats = (float2*)d_ws;                              // [MROWS]
    float* kwp = (float*)(stats + MROWS);                       // [32][768]
    float* skv = kwp + 32 * 768;                                // [32]
    float* ckv = skv + 32;                                      // [32]
    unsigned short* aligned = (unsigned short*)(ckv + 32);      // [MROWS][768]
    unsigned short* UNION = aligned + (size_t)MROWS * 768;      // awb -> Qn -> oh
    unsigned short* kbuf = UNION + (size_t)MTOK * 3072;         // [MROWS][32]
    unsigned short* qbuf = kbuf + (size_t)MROWS * 32;           // [MTOK][32]
    unsigned short* owb  = qbuf + (size_t)MTOK * 32;            // [768][3072]

    unsigned short* awb = UNION;

    // 0. weight conversions + LN folding precompute
    {
        long n = (long)NL * 768 * 768;
        conv_f32_bf16<<<(int)(n / 8 / 256), 256, 0, stream>>>(aw, awb, n);
        long n2 = (long)768 * 3072;
        conv_f32_bf16<<<(int)(n2 / 8 / 256), 256, 0, stream>>>(ow, owb, n2);
        wtrans<<<32, 256, 0, stream>>>(kw, kvg, kvb, kbias, kwp, skv, ckv);
    }

    // 1. aligner GEMM: 256^2, 2 LDS buffers (64KB), VGPR<=128 -> 2 blocks/CU
    gemm_f32a<<<1248, 512, 0, stream>>>(
        reps, awb, ab, aligned,
        (long)MTOK * 768, (long)768 * 768, 768,
        768L, (long)NL * 768);

    // 2. k projection + fused row stats
    proj32k_stats<<<MROWS / 128, 256, 0, stream>>>(
        aligned, kwp, skv, ckv, kbuf, stats);

    // 3. q side: LN(base) -> Qn, then proj32 (awb dead, reuse UNION)
    unsigned short* Qn = UNION;
    ln_rows_f32<<<MTOK / 4, 256, 0, stream>>>(base, Qn, qg, qbeta);
    proj32<<<MTOK / 128, 256, 0, stream>>>(Qn, qw, qbias, qbuf);

    // 4. attention on raw aligned (Qn dead, reuse UNION for oh)
    unsigned short* oh = UNION;
    attn2<<<MTOK / 4, 256, 0, stream>>>(qbuf, kbuf, aligned, stats, kvg, kvb, oh);

    // 5. out = out_heads @ out_w^T + out_b (64x128 tiles, 768 blocks)
    gemm_bf16_nt<<<768, 256, 0, stream>>>(oh, owb, obias, out, 3072, 768L);
}

// Round 17
// 429.092 us; speedup vs baseline: 5.5547x; 1.0107x over previous
//
#include <hip/hip_runtime.h>
#include <stdint.h>

#define NB 8
#define NT 1024
#define ND 768
#define NV 768
#define NL 13
#define MTOK (NB*NT)          // 8192
#define MROWS (MTOK*NL)       // 106496

typedef __attribute__((ext_vector_type(8))) short short8;
typedef __attribute__((ext_vector_type(4))) float f32x4;

__device__ __forceinline__ unsigned short f2bf(float f) {
    union { float f; unsigned u; } v; v.f = f;
    unsigned r = v.u + 0x7FFFu + ((v.u >> 16) & 1u);
    return (unsigned short)(r >> 16);
}
__device__ __forceinline__ float bf2f(unsigned short u) {
    union { unsigned u; float f; } v; v.u = ((unsigned)u) << 16;
    return v.f;
}
__device__ __forceinline__ unsigned cvtpk(float lo, float hi) {
    unsigned r;
    asm("v_cvt_pk_bf16_f32 %0, %1, %2" : "=v"(r) : "v"(lo), "v"(hi));
    return r;
}
__device__ __forceinline__ void gload16(const void* g, void* l) {
    __builtin_amdgcn_global_load_lds(
        (const __attribute__((address_space(1))) unsigned int*)g,
        (__attribute__((address_space(3))) unsigned int*)l, 16, 0, 0);
}

#define PHB { __builtin_amdgcn_s_barrier(); __builtin_amdgcn_sched_barrier(0); }

// ---------------------------------------------------------------------------
// fp32 -> bf16 bulk convert (weights only)
// ---------------------------------------------------------------------------
__global__ __launch_bounds__(256) void conv_f32_bf16(
    const float* __restrict__ s, unsigned short* __restrict__ d, long n)
{
    long i = ((long)blockIdx.x * 256 + threadIdx.x) * 8;
    long st = (long)gridDim.x * 2048;
    for (; i < n; i += st) {
        float4 a = *(const float4*)(s + i);
        float4 b = *(const float4*)(s + i + 4);
        ushort4 u0, u1;
        u0.x = f2bf(a.x); u0.y = f2bf(a.y); u0.z = f2bf(a.z); u0.w = f2bf(a.w);
        u1.x = f2bf(b.x); u1.y = f2bf(b.y); u1.z = f2bf(b.z); u1.w = f2bf(b.w);
        *(ushort4*)(d + i)     = u0;
        *(ushort4*)(d + i + 4) = u1;
    }
}

// ---------------------------------------------------------------------------
// GEMM1 (frozen at R16 best): C(bf16) = A(fp32) * B(bf16)^T + bias.
// 256x256 tile, 8 waves, chunk-major LDS, 2 buffers, reg staging,
// 1 barrier per K-tile.  265 us across 9 structural variants.
// ---------------------------------------------------------------------------
__global__ __launch_bounds__(512, 2) void gemm_f32a(
    const float* __restrict__ A, const unsigned short* __restrict__ B,
    const float* __restrict__ biasBase, unsigned short* __restrict__ C,
    long aLS, long bLS, int biasLS, long cLayerOff, long cRowStride)
{
    __shared__ __align__(16) unsigned short lsA[2][4 * 256 * 8];  // 16KB/buf
    __shared__ __align__(16) unsigned short lsB[2][4 * 256 * 8];

    const int bid = blockIdx.x;
    const int xcd = bid & 7, slot = bid >> 3;        // 156 slots per XCD
    const int grp = xcd * 52 + slot / 3;             // 0..415
    const int nx  = slot % 3;
    const int l   = grp >> 5;                        // layer 0..12
    const long m0 = (long)(grp & 31) * 256;
    const long n0 = (long)nx * 256;

    const int t = threadIdx.x, lane = t & 63, wave = t >> 6;

    const float* Ab = A + (size_t)l * aLS;
    const unsigned short* Bb = B + (size_t)l * bLS;
    const float* bias = biasBase + (size_t)l * biasLS;

    const int sRow  = t >> 1;
    const int sHalf = t & 1;
    const float* aSrc = Ab + (m0 + sRow) * (size_t)768 + sHalf * 16;
    const unsigned short* bSrc = Bb + (n0 + sRow) * (size_t)768 + sHalf * 16;

    const int wm = (wave >> 2) * 128;    // 2 M-wave groups
    const int wn = (wave & 3) * 64;      // 4 N-wave groups
    const int lr = lane & 15;
    const int g4 = lane >> 4;

    f32x4 acc[8][4];
#pragma unroll
    for (int i = 0; i < 8; i++)
#pragma unroll
        for (int j = 0; j < 4; j++) acc[i][j] = (f32x4){0.f, 0.f, 0.f, 0.f};

    f32x4 ra0[4], ra1[4];
    short8 rb0[2], rb1[2];

#define LOADA(R, K0) { _Pragma("unroll") \
    for (int i_ = 0; i_ < 4; i_++) (R)[i_] = *(const f32x4*)(aSrc + (K0) + i_ * 4); }
#define LOADB(R, K0) { _Pragma("unroll") \
    for (int j_ = 0; j_ < 2; j_++) (R)[j_] = *(const short8*)(bSrc + (K0) + j_ * 8); }
#define WRITEA(R, BUF) { unsigned short* la_ = lsA[BUF]; \
    uint4 w0_, w1_; \
    w0_.x = cvtpk((R)[0][0], (R)[0][1]); w0_.y = cvtpk((R)[0][2], (R)[0][3]); \
    w0_.z = cvtpk((R)[1][0], (R)[1][1]); w0_.w = cvtpk((R)[1][2], (R)[1][3]); \
    w1_.x = cvtpk((R)[2][0], (R)[2][1]); w1_.y = cvtpk((R)[2][2], (R)[2][3]); \
    w1_.z = cvtpk((R)[3][0], (R)[3][1]); w1_.w = cvtpk((R)[3][2], (R)[3][3]); \
    *(uint4*)&la_[(2 * sHalf + 0) * 2048 + sRow * 8] = w0_; \
    *(uint4*)&la_[(2 * sHalf + 1) * 2048 + sRow * 8] = w1_; }
#define WRITEB(R, BUF) { unsigned short* lb_ = lsB[BUF]; \
    *(short8*)&lb_[(2 * sHalf + 0) * 2048 + sRow * 8] = (R)[0]; \
    *(short8*)&lb_[(2 * sHalf + 1) * 2048 + sRow * 8] = (R)[1]; }

#define TILE(KS, RLA, RLB, RWA, RWB, DOL, DOW) { \
    const unsigned short* pa_ = lsA[(KS) & 1]; \
    const unsigned short* pb_ = lsB[(KS) & 1]; \
    if (DOL) { LOADA(RLA, ((KS) + 2) * 32); LOADB(RLB, ((KS) + 2) * 32); } \
    short8 bv_[4], af_[8]; \
    _Pragma("unroll") \
    for (int ni_ = 0; ni_ < 4; ni_++) \
        bv_[ni_] = *(const short8*)&pb_[g4 * 2048 + (wn + ni_ * 16 + lr) * 8]; \
    _Pragma("unroll") \
    for (int mi_ = 0; mi_ < 8; mi_++) \
        af_[mi_] = *(const short8*)&pa_[g4 * 2048 + (wm + mi_ * 16 + lr) * 8]; \
    __builtin_amdgcn_s_setprio(1); \
    _Pragma("unroll") \
    for (int mi_ = 0; mi_ < 8; mi_++) \
        _Pragma("unroll") \
        for (int ni_ = 0; ni_ < 4; ni_++) \
            acc[mi_][ni_] = __builtin_amdgcn_mfma_f32_16x16x32_bf16( \
                af_[mi_], bv_[ni_], acc[mi_][ni_], 0, 0, 0); \
    __builtin_amdgcn_s_setprio(0); \
    if (DOW) { WRITEA(RWA, ((KS) + 1) & 1); WRITEB(RWB, ((KS) + 1) & 1); } \
    asm volatile("s_waitcnt lgkmcnt(0)" ::: "memory"); PHB; }

    LOADA(ra0, 0);  LOADB(rb0, 0);
    LOADA(ra1, 32); LOADB(rb1, 32);
    WRITEA(ra0, 0); WRITEB(rb0, 0);
    __syncthreads();

    for (int tp = 0; tp < 20; tp += 2) {
        TILE(tp,     ra0, rb0, ra1, rb1, 1, 1);
        TILE(tp + 1, ra1, rb1, ra0, rb0, 1, 1);
    }
    TILE(20, ra0, rb0, ra1, rb1, 1, 1);
    TILE(21, ra1, rb1, ra0, rb0, 1, 1);
    TILE(22, ra0, rb0, ra1, rb1, 0, 1);
    TILE(23, ra1, rb1, ra0, rb0, 0, 0);

#undef TILE
#undef WRITEB
#undef WRITEA
#undef LOADB
#undef LOADA

#pragma unroll
    for (int ni = 0; ni < 4; ni++) {
        long col = n0 + wn + ni * 16 + lr;
        float bvs = bias[col];
#pragma unroll
        for (int mi = 0; mi < 8; mi++) {
#pragma unroll
            for (int r = 0; r < 4; r++) {
                long grow = m0 + wm + mi * 16 + g4 * 4 + r;
                size_t coff = (size_t)grow * cRowStride + (size_t)l * cLayerOff + col;
                C[coff] = f2bf(acc[mi][ni][r] + bvs);
            }
        }
    }
}

// ---------------------------------------------------------------------------
// GEMM2: C(f32) = A(bf16) * B(bf16)^T + bias.  64x128 tile, BK=32, gload
// staging + XOR swizzle (R6/R10-verified), grid 768 = 8 x 16 x 6.
// ---------------------------------------------------------------------------
__global__ __launch_bounds__(256) void gemm_bf16_nt(
    const unsigned short* __restrict__ A, const unsigned short* __restrict__ B,
    const float* __restrict__ bias, float* __restrict__ C,
    int K, long cRowStride)
{
    __shared__ __align__(16) unsigned short lsA[2][64 * 32];
    __shared__ __align__(16) unsigned short lsB[2][128 * 32];

    const int bid = blockIdx.x;
    const int xcd = bid & 7, slot = bid >> 3;        // 96 slots per XCD
    const int grp = xcd * 16 + slot / 6;             // 0..127 m-blocks
    const int nx  = slot % 6;
    const long m0 = (long)grp * 64;
    const long n0 = (long)nx * 128;

    const int t = threadIdx.x, lane = t & 63, wave = t >> 6;

    const int srow = wave * 16 + (lane >> 2);        // 0..63
    const int schk = (lane & 3) ^ ((lane >> 3) & 3);
    const int dS   = wave * 1024 + lane * 16;

    const int wm = (wave >> 1) * 32;
    const int wn = (wave & 1) * 64;
    const int lr = lane & 15;
    const int g4 = lane >> 4;
    const int kg = g4 * 8;
    const int swz = ((lr >> 1) & 3) * 8;

    const unsigned short* aSp  = A + (m0 + srow) * (size_t)K + schk * 8;
    const unsigned short* bSp0 = B + (n0 + srow) * (size_t)K + schk * 8;
    const unsigned short* bSp1 = B + (n0 + 64 + srow) * (size_t)K + schk * 8;

    f32x4 acc[2][4];
#pragma unroll
    for (int i = 0; i < 2; i++)
#pragma unroll
        for (int j = 0; j < 4; j++) acc[i][j] = (f32x4){0.f, 0.f, 0.f, 0.f};

    auto STAGE = [&](int buf, int k0) {
        char* la = (char*)lsA[buf];
        char* lb = (char*)lsB[buf];
        gload16(aSp + k0, la + dS);
        gload16(bSp0 + k0, lb + dS);
        gload16(bSp1 + k0, lb + 4096 + dS);
    };
    auto COMP = [&](int buf) {
        short8 af[2], bv[4];
        const unsigned short* pa = lsA[buf];
        const unsigned short* pb = lsB[buf];
#pragma unroll
        for (int mi = 0; mi < 2; mi++)
            af[mi] = *(const short8*)&pa[(wm + mi * 16 + lr) * 32 + (kg ^ swz)];
#pragma unroll
        for (int ni = 0; ni < 4; ni++)
            bv[ni] = *(const short8*)&pb[(wn + ni * 16 + lr) * 32 + (kg ^ swz)];
#pragma unroll
        for (int mi = 0; mi < 2; mi++)
#pragma unroll
            for (int ni = 0; ni < 4; ni++)
                acc[mi][ni] = __builtin_amdgcn_mfma_f32_16x16x32_bf16(
                    af[mi], bv[ni], acc[mi][ni], 0, 0, 0);
    };

    STAGE(0, 0);
    __syncthreads();
    int cur = 0;
    const int nst = K >> 5;
    for (int ks = 1; ks < nst; ks++) {
        STAGE(cur ^ 1, ks * 32);
        COMP(cur);
        __syncthreads();
        cur ^= 1;
    }
    COMP(cur);

#pragma unroll
    for (int ni = 0; ni < 4; ni++) {
        long col = n0 + wn + ni * 16 + lr;
        float bvs = bias[col];
#pragma unroll
        for (int mi = 0; mi < 2; mi++) {
#pragma unroll
            for (int r = 0; r < 4; r++) {
                long grow = m0 + wm + mi * 16 + g4 * 4 + r;
                C[(size_t)grow * cRowStride + col] = acc[mi][ni][r] + bvs;
            }
        }
    }
}

// ---------------------------------------------------------------------------
// Fold kvln gamma into k_w; compute s_k = sum(kw*g), c_k = kw.b + k_bias.
// ---------------------------------------------------------------------------
__global__ __launch_bounds__(256) void wtrans(
    const float* __restrict__ kw, const float* __restrict__ kvg,
    const float* __restrict__ kvb, const float* __restrict__ kbias,
    float* __restrict__ kwp, float* __restrict__ skv, float* __restrict__ ckv)
{
    __shared__ float red[8];
    const int q = blockIdx.x, t = threadIdx.x;
    const int lane = t & 63, wave = t >> 6;
    float s = 0.f, c = 0.f;
    for (int v = t; v < 768; v += 256) {
        float w = kw[q * 768 + v];
        float wp = w * kvg[v];
        kwp[q * 768 + v] = wp;
        s += wp;
        c += w * kvb[v];
    }
#pragma unroll
    for (int off = 1; off < 64; off <<= 1) {
        s += __shfl_xor(s, off);
        c += __shfl_xor(c, off);
    }
    if (lane == 0) { red[wave] = s; red[4 + wave] = c; }
    __syncthreads();
    if (t == 0) {
        skv[q] = red[0] + red[1] + red[2] + red[3];
        ckv[q] = red[4] + red[5] + red[6] + red[7] + kbias[q];
    }
}

// ---------------------------------------------------------------------------
// LayerNorm rows of 768 (fp32 src) -> bf16.  Q side only.
// ---------------------------------------------------------------------------
__global__ __launch_bounds__(256) void ln_rows_f32(
    const float* __restrict__ src, unsigned short* __restrict__ dst,
    const float* __restrict__ gam, const float* __restrict__ bet)
{
    const int lane = threadIdx.x & 63;
    const int wave = threadIdx.x >> 6;
    const size_t row = (size_t)blockIdx.x * 4 + wave;

    float x[3][4];
    float s = 0.f, sq = 0.f;
#pragma unroll
    for (int i = 0; i < 3; i++) {
        int v = i * 256 + lane * 4;
        float4 f = *(const float4*)(src + row * 768 + v);
        x[i][0] = f.x; x[i][1] = f.y; x[i][2] = f.z; x[i][3] = f.w;
#pragma unroll
        for (int e = 0; e < 4; e++) { s += x[i][e]; sq += x[i][e] * x[i][e]; }
    }
#pragma unroll
    for (int off = 1; off < 64; off <<= 1) {
        s  += __shfl_xor(s, off);
        sq += __shfl_xor(sq, off);
    }
    float mean = s * (1.f / 768.f);
    float var  = sq * (1.f / 768.f) - mean * mean;
    float rs   = rsqrtf(var + 1e-5f);
#pragma unroll
    for (int i = 0; i < 3; i++) {
        int v = i * 256 + lane * 4;
        float4 gg = *(const float4*)(gam + v);
        float4 bb = *(const float4*)(bet + v);
        ushort4 o;
        o.x = f2bf((x[i][0] - mean) * rs * gg.x + bb.x);
        o.y = f2bf((x[i][1] - mean) * rs * gg.y + bb.y);
        o.z = f2bf((x[i][2] - mean) * rs * gg.z + bb.z);
        o.w = f2bf((x[i][3] - mean) * rs * gg.w + bb.w);
        *(ushort4*)(dst + row * 768 + v) = o;
    }
}

// ---------------------------------------------------------------------------
// proj32: out[M][32] = A[M][768](bf16) @ W[32][768](f32)^T + bias (plain).
// ---------------------------------------------------------------------------
__global__ __launch_bounds__(256) void proj32(
    const unsigned short* __restrict__ A, const float* __restrict__ W,
    const float* __restrict__ bias, unsigned short* __restrict__ out)
{
    __shared__ __align__(16) unsigned short lsW[32 * 776];
    __shared__ __align__(16) unsigned short lsA[128 * 40];
    const int t = threadIdx.x;

#pragma unroll
    for (int i = 0; i < 24; i++) {
        int fi = t + i * 256;
        int row = fi / 192;
        int c4  = fi % 192;
        float4 f = *(const float4*)(W + row * 768 + c4 * 4);
        ushort4 u;
        u.x = f2bf(f.x); u.y = f2bf(f.y); u.z = f2bf(f.z); u.w = f2bf(f.w);
        *(ushort4*)&lsW[row * 776 + c4 * 4] = u;
    }

    const size_t m0 = (size_t)blockIdx.x * 128;
    const int lane = t & 63, wave = t >> 6;
    const int wm = wave * 32;
    const int lr = lane & 15, kg = (lane >> 4) * 8;
    const int row_s = t >> 3, c4s = t & 7;

    f32x4 acc[2][2];
#pragma unroll
    for (int i = 0; i < 2; i++)
#pragma unroll
        for (int j = 0; j < 2; j++) acc[i][j] = (f32x4){0.f, 0.f, 0.f, 0.f};

    __syncthreads();

    for (int k0 = 0; k0 < 768; k0 += 32) {
#pragma unroll
        for (int i = 0; i < 4; i++) {
            int row = row_s + 32 * i;
            ushort4 v = *(const ushort4*)(A + (m0 + row) * 768 + k0 + c4s * 4);
            *(ushort4*)&lsA[row * 40 + c4s * 4] = v;
        }
        __syncthreads();
        short8 af[2], bw[2];
#pragma unroll
        for (int mi = 0; mi < 2; mi++)
            af[mi] = *(const short8*)&lsA[(wm + mi * 16 + lr) * 40 + kg];
#pragma unroll
        for (int ni = 0; ni < 2; ni++)
            bw[ni] = *(const short8*)&lsW[(ni * 16 + lr) * 776 + k0 + kg];
#pragma unroll
        for (int mi = 0; mi < 2; mi++)
#pragma unroll
            for (int ni = 0; ni < 2; ni++)
                acc[mi][ni] = __builtin_amdgcn_mfma_f32_16x16x32_bf16(
                    af[mi], bw[ni], acc[mi][ni], 0, 0, 0);
        __syncthreads();
    }

#pragma unroll
    for (int ni = 0; ni < 2; ni++) {
        int col = ni * 16 + lr;
        float bv = bias[col];
#pragma unroll
        for (int mi = 0; mi < 2; mi++) {
#pragma unroll
            for (int r = 0; r < 4; r++) {
                size_t grow = m0 + wm + mi * 16 + (lane >> 4) * 4 + r;
                out[grow * 32 + col] = f2bf(acc[mi][ni][r] + bv);
            }
        }
    }
}

// ---------------------------------------------------------------------------
// proj32k_stats: k = rs*(dot(x_raw, kwp) - mean*s_k) + c_k, with row stats
// computed in the K-loop.  NEW: 16B/lane staging (short8, 2 issues/step)
// and 4-lane quad shuffle-reduce for stats.  LDS layout (pad-40) and the
// MFMA read path are unchanged from the verified version.
// ---------------------------------------------------------------------------
__global__ __launch_bounds__(256) void proj32k_stats(
    const unsigned short* __restrict__ A, const float* __restrict__ W,
    const float* __restrict__ skv, const float* __restrict__ ckv,
    unsigned short* __restrict__ out, float2* __restrict__ st)
{
    __shared__ __align__(16) unsigned short lsW[32 * 776];
    __shared__ __align__(16) unsigned short lsA[128 * 40];
    __shared__ float2 lstat[128];
    const int t = threadIdx.x;

#pragma unroll
    for (int i = 0; i < 24; i++) {
        int fi = t + i * 256;
        int row = fi / 192;
        int c4  = fi % 192;
        float4 f = *(const float4*)(W + row * 768 + c4 * 4);
        ushort4 u;
        u.x = f2bf(f.x); u.y = f2bf(f.y); u.z = f2bf(f.z); u.w = f2bf(f.w);
        *(ushort4*)&lsW[row * 776 + c4 * 4] = u;
    }

    const size_t m0 = (size_t)blockIdx.x * 128;
    const int lane = t & 63, wave = t >> 6;
    const int wm = wave * 32;
    const int lr = lane & 15, kg = (lane >> 4) * 8;
    const int rq = t >> 2;        // 0..63 (row within half-tile)
    const int cq = t & 3;         // 16B chunk 0..3

    f32x4 acc[2][2];
#pragma unroll
    for (int i = 0; i < 2; i++)
#pragma unroll
        for (int j = 0; j < 2; j++) acc[i][j] = (f32x4){0.f, 0.f, 0.f, 0.f};

    float s_[2] = {0.f, 0.f}, sq_[2] = {0.f, 0.f};

    __syncthreads();

    for (int k0 = 0; k0 < 768; k0 += 32) {
#pragma unroll
        for (int i = 0; i < 2; i++) {
            int row = rq + 64 * i;
            short8 v = *(const short8*)(A + (m0 + row) * 768 + k0 + cq * 8);
            *(short8*)&lsA[row * 40 + cq * 8] = v;
#pragma unroll
            for (int e = 0; e < 8; e++) {
                float x = bf2f((unsigned short)v[e]);
                s_[i] += x; sq_[i] += x * x;
            }
        }
        __syncthreads();
        short8 af[2], bw[2];
#pragma unroll
        for (int mi = 0; mi < 2; mi++)
            af[mi] = *(const short8*)&lsA[(wm + mi * 16 + lr) * 40 + kg];
#pragma unroll
        for (int ni = 0; ni < 2; ni++)
            bw[ni] = *(const short8*)&lsW[(ni * 16 + lr) * 776 + k0 + kg];
#pragma unroll
        for (int mi = 0; mi < 2; mi++)
#pragma unroll
            for (int ni = 0; ni < 2; ni++)
                acc[mi][ni] = __builtin_amdgcn_mfma_f32_16x16x32_bf16(
                    af[mi], bw[ni], acc[mi][ni], 0, 0, 0);
        __syncthreads();
    }

    // finish stats: 4 threads (cq=0..3) hold chunk partials per row
#pragma unroll
    for (int i = 0; i < 2; i++) {
#pragma unroll
        for (int off = 1; off < 4; off <<= 1) {
            s_[i]  += __shfl_xor(s_[i], off);
            sq_[i] += __shfl_xor(sq_[i], off);
        }
    }
    if (cq == 0) {
#pragma unroll
        for (int i = 0; i < 2; i++) {
            int row = rq + 64 * i;
            float mean = s_[i] * (1.f / 768.f);
            float var  = sq_[i] * (1.f / 768.f) - mean * mean;
            float2 sv = make_float2(mean, rsqrtf(var + 1e-5f));
            lstat[row] = sv;
            st[m0 + row] = sv;
        }
    }
    __syncthreads();

#pragma unroll
    for (int ni = 0; ni < 2; ni++) {
        int col = ni * 16 + lr;
        float sk = skv[col], ck = ckv[col];
#pragma unroll
        for (int mi = 0; mi < 2; mi++) {
#pragma unroll
            for (int r = 0; r < 4; r++) {
                int lrow = wm + mi * 16 + (lane >> 4) * 4 + r;
                float2 s2 = lstat[lrow];
                out[(m0 + lrow) * 32 + col] =
                    f2bf(s2.y * (acc[mi][ni][r] - s2.x * sk) + ck);
            }
        }
    }
}

// ---------------------------------------------------------------------------
// Attention on RAW aligned values with LN folded in.  One wave per token.
// NEW: 16B+8B per-lane PV loads (short8 covering elems [lane*8, lane*8+8)
// and ushort4 covering [512+lane*4, 512+lane*4+4)); outputs re-tiled to
// match.  Math identical.
// ---------------------------------------------------------------------------
__global__ __launch_bounds__(256) void attn2(
    const unsigned short* __restrict__ qb, const unsigned short* __restrict__ kb,
    const unsigned short* __restrict__ kv, const float2* __restrict__ st,
    const float* __restrict__ gv, const float* __restrict__ bvv,
    unsigned short* __restrict__ oh)
{
    __shared__ float lat[4][4][13];
    __shared__ float latc[4][4];
    const int t = threadIdx.x, lane = t & 63, wave = t >> 6;
    const size_t m = (size_t)blockIdx.x * 4 + wave;

    if (lane < 32) {
        int j = lane;
        float qv = bf2f(qb[m * 32 + j]);
        float p[13];
#pragma unroll
        for (int l = 0; l < 13; l++)
            p[l] = qv * bf2f(kb[(m * 13 + l) * 32 + j]);
#pragma unroll
        for (int off = 1; off < 8; off <<= 1)
#pragma unroll
            for (int l = 0; l < 13; l++) p[l] += __shfl_xor(p[l], off);

        const float sc = 0.17677669529663687f; // 1 / (sqrt(8) * 2)
        float mx = -1e30f;
#pragma unroll
        for (int l = 0; l < 13; l++) { p[l] *= sc; mx = fmaxf(mx, p[l]); }
        float se = 0.f;
#pragma unroll
        for (int l = 0; l < 13; l++) { p[l] = __expf(p[l] - mx); se += p[l]; }
        float inv = 1.f / se;
        if ((j & 7) == 0) {
            int h = j >> 3;
            float corr = 0.f;
#pragma unroll
            for (int l = 0; l < 13; l++) {
                float2 s_ = st[m * 13 + l];
                float wl = p[l] * inv * s_.y;
                lat[wave][h][l] = wl;
                corr += wl * s_.x;
            }
            latc[wave][h] = corr;
        }
    }
    __syncthreads();

    // gamma/beta: elems lane*8..lane*8+7 and 512+lane*4..512+lane*4+3
    f32x4 gA[2], bA[2], gB, bB;
#pragma unroll
    for (int j = 0; j < 2; j++) {
        gA[j] = *(const f32x4*)(gv + lane * 8 + j * 4);
        bA[j] = *(const f32x4*)(bvv + lane * 8 + j * 4);
    }
    gB = *(const f32x4*)(gv + 512 + lane * 4);
    bB = *(const f32x4*)(bvv + 512 + lane * 4);

    float accA[4][8], accB[4][4];
#pragma unroll
    for (int h = 0; h < 4; h++) {
#pragma unroll
        for (int e = 0; e < 8; e++) accA[h][e] = 0.f;
#pragma unroll
        for (int e = 0; e < 4; e++) accB[h][e] = 0.f;
    }

    for (int l = 0; l < 13; l++) {
        float al[4];
#pragma unroll
        for (int h = 0; h < 4; h++) al[h] = lat[wave][h][l];
        const unsigned short* rowp = kv + (m * 13 + l) * 768;
        short8 u8 = *(const short8*)(rowp + lane * 8);
        ushort4 u4 = *(const ushort4*)(rowp + 512 + lane * 4);
        float xA[8] = {
            bf2f((unsigned short)u8[0]), bf2f((unsigned short)u8[1]),
            bf2f((unsigned short)u8[2]), bf2f((unsigned short)u8[3]),
            bf2f((unsigned short)u8[4]), bf2f((unsigned short)u8[5]),
            bf2f((unsigned short)u8[6]), bf2f((unsigned short)u8[7])};
        float xB[4] = {bf2f(u4.x), bf2f(u4.y), bf2f(u4.z), bf2f(u4.w)};
#pragma unroll
        for (int h = 0; h < 4; h++) {
#pragma unroll
            for (int e = 0; e < 8; e++) accA[h][e] += al[h] * xA[e];
#pragma unroll
            for (int e = 0; e < 4; e++) accB[h][e] += al[h] * xB[e];
        }
    }
#pragma unroll
    for (int h = 0; h < 4; h++) {
        float ch = latc[wave][h];
        unsigned short* ohp = oh + m * 3072 + h * 768;
#pragma unroll
        for (int j = 0; j < 2; j++) {
            ushort4 o;
            o.x = f2bf(gA[j][0] * (accA[h][j * 4 + 0] - ch) + bA[j][0]);
            o.y = f2bf(gA[j][1] * (accA[h][j * 4 + 1] - ch) + bA[j][1]);
            o.z = f2bf(gA[j][2] * (accA[h][j * 4 + 2] - ch) + bA[j][2]);
            o.w = f2bf(gA[j][3] * (accA[h][j * 4 + 3] - ch) + bA[j][3]);
            *(ushort4*)(ohp + lane * 8 + j * 4) = o;
        }
        ushort4 o;
        o.x = f2bf(gB[0] * (accB[h][0] - ch) + bB[0]);
        o.y = f2bf(gB[1] * (accB[h][1] - ch) + bB[1]);
        o.z = f2bf(gB[2] * (accB[h][2] - ch) + bB[2]);
        o.w = f2bf(gB[3] * (accB[h][3] - ch) + bB[3]);
        *(ushort4*)(ohp + 512 + lane * 4) = o;
    }
}

// ---------------------------------------------------------------------------
extern "C" void kernel_launch(void* const* d_in, const int* in_sizes, int n_in,
                              void* d_out, int out_size, void* d_ws, size_t ws_size,
                              hipStream_t stream) {
    const float* base  = (const float*)d_in[0];
    const float* reps  = (const float*)d_in[1];
    const float* aw    = (const float*)d_in[2];
    const float* ab    = (const float*)d_in[3];
    const float* qg    = (const float*)d_in[4];
    const float* qbeta = (const float*)d_in[5];
    const float* kvg   = (const float*)d_in[6];
    const float* kvb   = (const float*)d_in[7];
    const float* qw    = (const float*)d_in[8];
    const float* qbias = (const float*)d_in[9];
    const float* kw    = (const float*)d_in[10];
    const float* kbias = (const float*)d_in[11];
    const float* ow    = (const float*)d_in[12];
    const float* obias = (const float*)d_in[13];
    float* out = (float*)d_out;

    float2* stats = (float2*)d_ws;                              // [MROWS]
    float* kwp = (float*)(stats + MROWS);                       // [32][768]
    float* skv = kwp + 32 * 768;                                // [32]
    float* ckv = skv + 32;                                      // [32]
    unsigned short* aligned = (unsigned short*)(ckv + 32);      // [MROWS][768]
    unsigned short* UNION = aligned + (size_t)MROWS * 768;      // awb -> Qn -> oh
    unsigned short* kbuf = UNION + (size_t)MTOK * 3072;         // [MROWS][32]
    unsigned short* qbuf = kbuf + (size_t)MROWS * 32;           // [MTOK][32]
    unsigned short* owb  = qbuf + (size_t)MTOK * 32;            // [768][3072]

    unsigned short* awb = UNION;

    // 0. weight conversions + LN folding precompute
    {
        long n = (long)NL * 768 * 768;
        conv_f32_bf16<<<(int)(n / 8 / 256), 256, 0, stream>>>(aw, awb, n);
        long n2 = (long)768 * 3072;
        conv_f32_bf16<<<(int)(n2 / 8 / 256), 256, 0, stream>>>(ow, owb, n2);
        wtrans<<<32, 256, 0, stream>>>(kw, kvg, kvb, kbias, kwp, skv, ckv);
    }

    // 1. aligner GEMM (frozen R16 config)
    gemm_f32a<<<1248, 512, 0, stream>>>(
        reps, awb, ab, aligned,
        (long)MTOK * 768, (long)768 * 768, 768,
        768L, (long)NL * 768);

    // 2. k projection + fused row stats (16B staging)
    proj32k_stats<<<MROWS / 128, 256, 0, stream>>>(
        aligned, kwp, skv, ckv, kbuf, stats);

    // 3. q side: LN(base) -> Qn, then proj32 (awb dead, reuse UNION)
    unsigned short* Qn = UNION;
    ln_rows_f32<<<MTOK / 4, 256, 0, stream>>>(base, Qn, qg, qbeta);
    proj32<<<MTOK / 128, 256, 0, stream>>>(Qn, qw, qbias, qbuf);

    // 4. attention on raw aligned (16B/8B PV loads)
    unsigned short* oh = UNION;
    attn2<<<MTOK / 4, 256, 0, stream>>>(qbuf, kbuf, aligned, stats, kvg, kvb, oh);

    // 5. out = out_heads @ out_w^T + out_b (64x128 tiles, 768 blocks)
    gemm_bf16_nt<<<768, 256, 0, stream>>>(oh, owb, obias, out, 3072, 768L);
}